// Round 1
// baseline (217.180 us; speedup 1.0000x reference)
//
#include <hip/hip_runtime.h>
#include <hip/hip_bf16.h>
#include <stdint.h>

#define DEV static __device__ __forceinline__

typedef __attribute__((ext_vector_type(8))) short   s16x8;
typedef __attribute__((ext_vector_type(8))) __bf16  bf16x8;
typedef __attribute__((ext_vector_type(4))) float   f32x4;

DEV float bf2f(short u){
  union{float f; uint32_t i;} x; x.i = ((uint32_t)(uint16_t)u) << 16; return x.f;
}
DEV short f2b(float f){           // round-to-nearest-even f32 -> bf16
  union{float f; uint32_t i;} x; x.f = f;
  uint32_t r = x.i + 0x7FFFu + ((x.i >> 16) & 1u);
  return (short)(r >> 16);
}
DEV bf16x8 as_bf(s16x8 v){ return __builtin_bit_cast(bf16x8, v); }

DEV void gload_lds16(const void* g, void* l){
  __builtin_amdgcn_global_load_lds((const __attribute__((address_space(1))) void*)g,
                                   (__attribute__((address_space(3))) void*)l, 16, 0, 0);
}

// ---------------- convert f32 -> bf16 (vectorized) ----------------
__global__ __launch_bounds__(256) void k_f32_to_bf16(const float* __restrict__ in,
                                                     short* __restrict__ out, int n){
  int i = (blockIdx.x * 256 + threadIdx.x) * 4;
  float4 v = *(const float4*)(in + i);
  short o[4] = { f2b(v.x), f2b(v.y), f2b(v.z), f2b(v.w) };
  *(uint2*)(out + i) = *(uint2*)o;
}

// ------------- weight transpose+convert: w[512][512] f32 -> wt[n][k] bf16 -------------
__global__ __launch_bounds__(256) void k_wt(const float* __restrict__ w, short* __restrict__ wt){
  __shared__ float tile[32][33];
  int bx = blockIdx.x * 32, by = blockIdx.y * 32;   // bx: n-block, by: k-block
  int tx = threadIdx.x, ty = threadIdx.y;           // (32, 8)
  for (int j = 0; j < 32; j += 8)
    tile[ty + j][tx] = w[(size_t)(by + ty + j) * 512 + bx + tx];
  __syncthreads();
  for (int j = 0; j < 32; j += 8)
    wt[(size_t)(bx + ty + j) * 512 + by + tx] = f2b(tile[tx][ty + j]);
}

// ---------------- RoPE cos/sin table: tab[s][j][{cos,sin}], s<1024, j<32 ----------------
__global__ __launch_bounds__(256) void k_table(float* __restrict__ tab){
  int idx = blockIdx.x * 256 + threadIdx.x;   // 32768
  int s = idx >> 5, j = idx & 31;
  float inv = __expf(-(float)j * (1.0f / 32.0f) * logf(10000.0f));
  float ang = (float)s * inv;
  tab[idx * 2 + 0] = cosf(ang);
  tab[idx * 2 + 1] = sinf(ang);
}

// ---------------- GEMM: C[m][n] = sum_k X[m][k] * Wt[n][k], M x 512 x 512, bf16 MFMA ----------------
template<int OUT_BF16>
__global__ __launch_bounds__(256) void k_gemm(const short* __restrict__ X,
                                              const short* __restrict__ Wt,
                                              void* __restrict__ Cout){
  __shared__ __align__(16) short Al[128 * 32];
  __shared__ __align__(16) short Bl[128 * 32];
  const int t = threadIdx.x;
  const int w = t >> 6, lane = t & 63, fr = lane & 15, fg = lane >> 4;
  const int bm = blockIdx.x * 128, bn = blockIdx.y * 128;
  const int wm = (w >> 1) * 64, wn = (w & 1) * 64;
  const int r8 = t >> 2, c8 = (t & 3) * 8;          // staging: row, col8
  f32x4 acc[4][4] = {};
  for (int k0 = 0; k0 < 512; k0 += 32){
    __syncthreads();
#pragma unroll
    for (int j = 0; j < 2; j++){
      const short* ga = X  + (size_t)(bm + j * 64 + r8) * 512 + (k0 + c8);
      const short* gb = Wt + (size_t)(bn + j * 64 + r8) * 512 + (k0 + c8);
      gload_lds16(ga, &Al[j * 2048 + w * 512]);
      gload_lds16(gb, &Bl[j * 2048 + w * 512]);
    }
    __syncthreads();
    s16x8 af[4], bv[4];
#pragma unroll
    for (int f = 0; f < 4; f++){
      af[f] = *(const s16x8*)(&Al[(wm + f * 16 + fr) * 32 + fg * 8]);
      bv[f] = *(const s16x8*)(&Bl[(wn + f * 16 + fr) * 32 + fg * 8]);
    }
#pragma unroll
    for (int i = 0; i < 4; i++)
#pragma unroll
      for (int jj = 0; jj < 4; jj++)
        acc[i][jj] = __builtin_amdgcn_mfma_f32_16x16x32_bf16(as_bf(af[i]), as_bf(bv[jj]),
                                                             acc[i][jj], 0, 0, 0);
  }
  const int row0 = bm + wm + fg * 4;
  const int col0 = bn + wn + fr;
  if (OUT_BF16){
    short* C = (short*)Cout;
#pragma unroll
    for (int i = 0; i < 4; i++)
#pragma unroll
      for (int jj = 0; jj < 4; jj++)
#pragma unroll
        for (int r = 0; r < 4; r++)
          C[(size_t)(row0 + i * 16 + r) * 512 + col0 + jj * 16] = f2b(acc[i][jj][r]);
  } else {
    float* C = (float*)Cout;
#pragma unroll
    for (int i = 0; i < 4; i++)
#pragma unroll
      for (int jj = 0; jj < 4; jj++)
#pragma unroll
        for (int r = 0; r < 4; r++)
          C[(size_t)(row0 + i * 16 + r) * 512 + col0 + jj * 16] = acc[i][jj][r];
  }
}

// ---------------- RoPE + scale + layout: raw[m][h*64+d] -> out[(b*8+h)*1024+s][d] ----------------
__global__ __launch_bounds__(256) void k_rope(const short* __restrict__ Xr,
                                              const float* __restrict__ tab,
                                              short* __restrict__ Xo, float scale){
  int idx = blockIdx.x * 256 + threadIdx.x;   // ((b*8+h)*1024+s)*32 + j
  int j  = idx & 31;
  int s  = (idx >> 5) & 1023;
  int bh = idx >> 15;
  int b = bh >> 3, h = bh & 7;
  size_t ib = (size_t)(b * 1024 + s) * 512 + h * 64 + j;
  float x1 = bf2f(Xr[ib]);
  float x2 = bf2f(Xr[ib + 32]);
  float c  = tab[(s * 32 + j) * 2 + 0];
  float sn = tab[(s * 32 + j) * 2 + 1];
  size_t ob = ((size_t)bh * 1024 + s) * 64 + j;
  Xo[ob]      = f2b((x1 * c - x2 * sn) * scale);
  Xo[ob + 32] = f2b((x2 * c + x1 * sn) * scale);
}

// ---------------- V layout: raw[m][h*64+d] -> Vt[(b*8+h)][d][s] ----------------
__global__ __launch_bounds__(256) void k_vt(const short* __restrict__ Vr, short* __restrict__ Vt){
  __shared__ short tile[64][66];
  int bh = blockIdx.x >> 4, s0 = (blockIdx.x & 15) * 64;
  int b = bh >> 3, h = bh & 7;
  int t = threadIdx.x;
  int r = t >> 2, cs = (t & 3) * 16;
#pragma unroll
  for (int i = 0; i < 2; i++){
    s16x8 v = *(const s16x8*)(Vr + (size_t)(b * 1024 + s0 + r) * 512 + h * 64 + cs + i * 8);
#pragma unroll
    for (int e = 0; e < 8; e++) tile[r][cs + i * 8 + e] = v[e];
  }
  __syncthreads();
  int d = t >> 2, ss = (t & 3) * 16;
  __align__(16) short tmp[16];
#pragma unroll
  for (int i = 0; i < 16; i++) tmp[i] = tile[ss + i][d];
  size_t ob = ((size_t)bh * 64 + d) * 1024 + s0 + ss;
  *(s16x8*)(Vt + ob)     = *(s16x8*)(tmp);
  *(s16x8*)(Vt + ob + 8) = *(s16x8*)(tmp + 8);
}

// ---------------- causal flash attention ----------------
// Q,K: (bh, s, 64) bf16 ; Vt: (bh, 64, 1024) bf16 ; O: [b*1024+q][h*64+d] bf16
__global__ __launch_bounds__(256) void k_attn(const short* __restrict__ Qb,
                                              const short* __restrict__ Kb,
                                              const short* __restrict__ Vt,
                                              short* __restrict__ O){
  __shared__ __align__(16) short Pl[4][16 * 72];
  const int bh = blockIdx.y, qt = blockIdx.x;
  const int t = threadIdx.x, w = t >> 6, lane = t & 63, fr = lane & 15, fg = lane >> 4;
  const int qw = qt * 64 + w * 16;                 // this wave's 16 q rows
  const short* Qp = Qb + (size_t)bh * 65536;
  const short* Kp = Kb + (size_t)bh * 65536;
  const short* Vp = Vt + (size_t)bh * 65536;
  short* myP = &Pl[w][0];

  s16x8 qf0 = *(const s16x8*)(Qp + (size_t)(qw + fr) * 64 + fg * 8);
  s16x8 qf1 = *(const s16x8*)(Qp + (size_t)(qw + fr) * 64 + 32 + fg * 8);

  f32x4 oacc[4] = {};
  float mrun[4] = {-1e30f, -1e30f, -1e30f, -1e30f};
  float lrun[4] = {0.f, 0.f, 0.f, 0.f};

  for (int kv0 = 0; kv0 < qw + 16; kv0 += 64){
    // ---- scores S = Q K^T : D[q][kv], 4 kv-frags ----
    f32x4 sc[4];
#pragma unroll
    for (int f = 0; f < 4; f++){
      s16x8 kf0 = *(const s16x8*)(Kp + (size_t)(kv0 + f * 16 + fr) * 64 + fg * 8);
      s16x8 kf1 = *(const s16x8*)(Kp + (size_t)(kv0 + f * 16 + fr) * 64 + 32 + fg * 8);
      f32x4 s = {};
      s = __builtin_amdgcn_mfma_f32_16x16x32_bf16(as_bf(qf0), as_bf(kf0), s, 0, 0, 0);
      s = __builtin_amdgcn_mfma_f32_16x16x32_bf16(as_bf(qf1), as_bf(kf1), s, 0, 0, 0);
      sc[f] = s;
    }
    // ---- causal mask (only diagonal tiles) ----
    if (kv0 + 63 > qw){
#pragma unroll
      for (int f = 0; f < 4; f++)
#pragma unroll
        for (int r = 0; r < 4; r++){
          int q = qw + fg * 4 + r, kv = kv0 + f * 16 + fr;
          if (kv > q) sc[f][r] = -1e30f;
        }
    }
    // ---- online softmax (row reduce across the 16-lane column group) ----
#pragma unroll
    for (int r = 0; r < 4; r++){
      float m_ = fmaxf(fmaxf(sc[0][r], sc[1][r]), fmaxf(sc[2][r], sc[3][r]));
#pragma unroll
      for (int off = 1; off < 16; off <<= 1) m_ = fmaxf(m_, __shfl_xor(m_, off, 64));
      float mnew = fmaxf(mrun[r], m_);
      float corr = __expf(mrun[r] - mnew);
      mrun[r] = mnew;
      float rs = 0.f;
#pragma unroll
      for (int f = 0; f < 4; f++){
        float p = __expf(sc[f][r] - mnew);
        sc[f][r] = p; rs += p;
      }
#pragma unroll
      for (int off = 1; off < 16; off <<= 1) rs += __shfl_xor(rs, off, 64);
      lrun[r] = lrun[r] * corr + rs;
#pragma unroll
      for (int jj = 0; jj < 4; jj++) oacc[jj][r] *= corr;
    }
    // ---- P (f32 D-frag) -> bf16 A-frag via per-wave LDS ----
#pragma unroll
    for (int f = 0; f < 4; f++)
#pragma unroll
      for (int r = 0; r < 4; r++)
        myP[(fg * 4 + r) * 72 + f * 16 + fr] = f2b(sc[f][r]);
    s16x8 pa0 = *(const s16x8*)(myP + fr * 72 + fg * 8);
    s16x8 pa1 = *(const s16x8*)(myP + fr * 72 + 32 + fg * 8);
    // ---- O += P V ----
#pragma unroll
    for (int jj = 0; jj < 4; jj++){
      s16x8 vf0 = *(const s16x8*)(Vp + (size_t)(jj * 16 + fr) * 1024 + kv0 + fg * 8);
      s16x8 vf1 = *(const s16x8*)(Vp + (size_t)(jj * 16 + fr) * 1024 + kv0 + 32 + fg * 8);
      oacc[jj] = __builtin_amdgcn_mfma_f32_16x16x32_bf16(as_bf(pa0), as_bf(vf0), oacc[jj], 0, 0, 0);
      oacc[jj] = __builtin_amdgcn_mfma_f32_16x16x32_bf16(as_bf(pa1), as_bf(vf1), oacc[jj], 0, 0, 0);
    }
  }
  const int b = bh >> 3, h = bh & 7;
#pragma unroll
  for (int jj = 0; jj < 4; jj++)
#pragma unroll
    for (int r = 0; r < 4; r++){
      int q = qw + fg * 4 + r;
      O[(size_t)(b * 1024 + q) * 512 + h * 64 + jj * 16 + fr] = f2b(oacc[jj][r] / lrun[r]);
    }
}

extern "C" void kernel_launch(void* const* d_in, const int* in_sizes, int n_in,
                              void* d_out, int out_size, void* d_ws, size_t ws_size,
                              hipStream_t stream){
  const float* query  = (const float*)d_in[0];
  const float* value  = (const float*)d_in[1];
  const float* key_in = (const float*)d_in[2];
  const float* Wq     = (const float*)d_in[3];
  const float* Wk     = (const float*)d_in[4];
  const float* Wv     = (const float*)d_in[5];
  const float* Wo     = (const float*)d_in[6];

  char* ws = (char*)d_ws;
  const size_t MB = 1ull << 20;
  // needs ~50.3 MB of workspace
  short* Xq  = (short*)(ws + 0 * MB);            // 8 MB, reused as Qrope
  short* Xk  = (short*)(ws + 8 * MB);            // 8 MB, reused as Krope
  short* Xv  = (short*)(ws + 16 * MB);           // 8 MB, reused as Vt
  short* Wqt = (short*)(ws + 24 * MB);
  short* Wkt = (short*)(ws + 24 * MB + 512 * 1024);
  short* Wvt = (short*)(ws + 25 * MB);
  short* Wot = (short*)(ws + 25 * MB + 512 * 1024);
  short* Qr  = (short*)(ws + 26 * MB);           // 8 MB, reused as O
  short* Kr  = (short*)(ws + 34 * MB);
  short* Vr  = (short*)(ws + 42 * MB);
  float* tab = (float*)(ws + 50 * MB);           // 256 KB

  const int n = 8192 * 512;
  k_f32_to_bf16<<<n / 1024, 256, 0, stream>>>(query,  Xq, n);
  k_f32_to_bf16<<<n / 1024, 256, 0, stream>>>(key_in, Xk, n);
  k_f32_to_bf16<<<n / 1024, 256, 0, stream>>>(value,  Xv, n);
  dim3 wb(32, 8), wg(16, 16);
  k_wt<<<wg, wb, 0, stream>>>(Wq, Wqt);
  k_wt<<<wg, wb, 0, stream>>>(Wk, Wkt);
  k_wt<<<wg, wb, 0, stream>>>(Wv, Wvt);
  k_wt<<<wg, wb, 0, stream>>>(Wo, Wot);
  k_table<<<128, 256, 0, stream>>>(tab);

  dim3 gg(64, 4);
  k_gemm<1><<<gg, 256, 0, stream>>>(Xq, Wqt, Qr);
  k_gemm<1><<<gg, 256, 0, stream>>>(Xk, Wkt, Kr);
  k_gemm<1><<<gg, 256, 0, stream>>>(Xv, Wvt, Vr);

  short* Qa = Xq;  short* Ka = Xk;  short* Va = Xv;  short* Oa = Qr;
  k_rope<<<8192, 256, 0, stream>>>(Qr, tab, Qa, 0.125f);
  k_rope<<<8192, 256, 0, stream>>>(Kr, tab, Ka, 1.0f);
  k_vt<<<1024, 256, 0, stream>>>(Vr, Va);

  dim3 ag(16, 64);
  k_attn<<<ag, 256, 0, stream>>>(Qa, Ka, Va, Oa);

  k_gemm<0><<<gg, 256, 0, stream>>>(Oa, Wot, d_out);
}

// Round 3
// 158.769 us; speedup vs baseline: 1.3679x; 1.3679x over previous
//
#include <hip/hip_runtime.h>
#include <hip/hip_bf16.h>
#include <stdint.h>

#define DEV static __device__ __forceinline__

typedef __attribute__((ext_vector_type(8))) short   s16x8;
typedef __attribute__((ext_vector_type(4))) short   s16x4;
typedef __attribute__((ext_vector_type(8))) __bf16  bf16x8;
typedef __attribute__((ext_vector_type(4))) float   f32x4;

DEV short f2b(float f){           // round-to-nearest-even f32 -> bf16
  union{float f; uint32_t i;} x; x.f = f;
  uint32_t r = x.i + 0x7FFFu + ((x.i >> 16) & 1u);
  return (short)(r >> 16);
}
DEV bf16x8 as_bf(s16x8 v){ return __builtin_bit_cast(bf16x8, v); }
DEV float fexp2(float x){ return __builtin_amdgcn_exp2f(x); }   // v_exp_f32: 2^x

DEV void gload_lds16(const void* g, void* l){
  __builtin_amdgcn_global_load_lds((const __attribute__((address_space(1))) void*)g,
                                   (__attribute__((address_space(3))) void*)l, 16, 0, 0);
}

// ---------------- fused convert f32 -> bf16 for query/key_in/value ----------------
__global__ __launch_bounds__(256) void k_conv3(const float* __restrict__ q,
                                               const float* __restrict__ k,
                                               const float* __restrict__ v,
                                               short* __restrict__ out){
  int z = blockIdx.z;
  const float* in = (z == 0) ? q : (z == 1) ? k : v;
  int i = (blockIdx.x * 256 + threadIdx.x) * 4;
  float4 val = *(const float4*)(in + i);
  short o[4] = { f2b(val.x), f2b(val.y), f2b(val.z), f2b(val.w) };
  *(uint2*)(out + (size_t)z * 4194304 + i) = *(uint2*)o;
}

// ------------- fused weight transpose+convert: 4x w[512][512] f32 -> wt[n][k] bf16 -------------
__global__ __launch_bounds__(256) void k_wt4(const float* __restrict__ w0,
                                             const float* __restrict__ w1,
                                             const float* __restrict__ w2,
                                             const float* __restrict__ w3,
                                             short* __restrict__ wt){
  __shared__ float tile[32][33];
  int z = blockIdx.z;
  const float* w = (z == 0) ? w0 : (z == 1) ? w1 : (z == 2) ? w2 : w3;
  short* o = wt + (size_t)z * 262144;
  int bx = blockIdx.x * 32, by = blockIdx.y * 32;   // bx: n-block, by: k-block
  int tx = threadIdx.x, ty = threadIdx.y;           // (32, 8)
  for (int j = 0; j < 32; j += 8)
    tile[ty + j][tx] = w[(size_t)(by + ty + j) * 512 + bx + tx];
  __syncthreads();
  for (int j = 0; j < 32; j += 8)
    o[(size_t)(bx + ty + j) * 512 + by + tx] = f2b(tile[tx][ty + j]);
}

// ---------------- RoPE cos/sin table: tab[s][j][{cos,sin}], s<1024, j<32 ----------------
__global__ __launch_bounds__(256) void k_table(float* __restrict__ tab){
  int idx = blockIdx.x * 256 + threadIdx.x;   // 32768
  int s = idx >> 5, j = idx & 31;
  float inv = __expf(-(float)j * (1.0f / 32.0f) * logf(10000.0f));
  float ang = (float)s * inv;
  tab[idx * 2 + 0] = cosf(ang);
  tab[idx * 2 + 1] = sinf(ang);
}

// ---------------- fused QKV GEMM + RoPE/layout epilogues ----------------
// C[m][n] = sum_k X[m][k] * Wcat[n][k];  sel = n/512 chooses {Q,K,V}
// Q: rope, *0.125*log2e, -> Qa[(b*8+h)*1024+s][64]
// K: rope,               -> Ka[(b*8+h)*1024+s][64]
// V:                     -> Vt[(b*8+h)*64+d][1024]
__global__ __launch_bounds__(256) void k_qkv(const short* __restrict__ Xq,
                                             const short* __restrict__ Xk,
                                             const short* __restrict__ Xv,
                                             const short* __restrict__ Wcat,
                                             const float* __restrict__ tab,
                                             short* __restrict__ Qa,
                                             short* __restrict__ Ka,
                                             short* __restrict__ Vt){
  __shared__ __align__(16) short Al[128 * 32];
  __shared__ __align__(16) short Bl[128 * 32];
  const int t = threadIdx.x;
  const int w = t >> 6, lane = t & 63, fr = lane & 15, fg = lane >> 4;
  const int sel = blockIdx.y >> 2;
  const short* X = (sel == 0) ? Xq : (sel == 1) ? Xk : Xv;
  const int bm = blockIdx.x * 128, bn = blockIdx.y * 128;
  const int wm = (w >> 1) * 64, wn = (w & 1) * 64;
  const int r8 = t >> 2, c8 = (t & 3) * 8;
  f32x4 acc[4][4] = {};
  for (int k0 = 0; k0 < 512; k0 += 32){
    __syncthreads();
#pragma unroll
    for (int j = 0; j < 2; j++){
      const short* ga = X    + (size_t)(bm + j * 64 + r8) * 512 + (k0 + c8);
      const short* gb = Wcat + (size_t)(bn + j * 64 + r8) * 512 + (k0 + c8);
      gload_lds16(ga, &Al[j * 2048 + w * 512]);
      gload_lds16(gb, &Bl[j * 2048 + w * 512]);
    }
    __syncthreads();
    s16x8 af[4], bv[4];
#pragma unroll
    for (int f = 0; f < 4; f++){
      af[f] = *(const s16x8*)(&Al[(wm + f * 16 + fr) * 32 + fg * 8]);
      bv[f] = *(const s16x8*)(&Bl[(wn + f * 16 + fr) * 32 + fg * 8]);
    }
#pragma unroll
    for (int i = 0; i < 4; i++)
#pragma unroll
      for (int jj = 0; jj < 4; jj++)
        acc[i][jj] = __builtin_amdgcn_mfma_f32_16x16x32_bf16(as_bf(af[i]), as_bf(bv[jj]),
                                                             acc[i][jj], 0, 0, 0);
  }
  const int row0 = bm + wm + fg * 4;         // + i*16 + r
  const int b = row0 >> 10;
  const int s_base = row0 & 1023;
  const int hh = (((blockIdx.y & 3) * 128) + wn) >> 6;   // head 0..7
  if (sel < 2){
    const float scale = (sel == 0) ? 0.125f * 1.44269504f : 1.0f;
    short* out = (sel == 0) ? Qa : Ka;
#pragma unroll
    for (int i = 0; i < 4; i++)
#pragma unroll
      for (int jj = 0; jj < 2; jj++){
        int d = jj * 16 + fr;                // 0..31
#pragma unroll
        for (int r = 0; r < 4; r++){
          int s = s_base + i * 16 + r;
          float2 cs = *(const float2*)(tab + (size_t)(s * 32 + d) * 2);
          float x1 = acc[i][jj][r], x2 = acc[i][jj + 2][r];
          size_t ob = ((size_t)((b * 8 + hh) * 1024 + s)) * 64 + d;
          out[ob]      = f2b((x1 * cs.x - x2 * cs.y) * scale);
          out[ob + 32] = f2b((x2 * cs.x + x1 * cs.y) * scale);
        }
      }
  } else {
#pragma unroll
    for (int i = 0; i < 4; i++)
#pragma unroll
      for (int jj = 0; jj < 4; jj++){
        int d = jj * 16 + fr;
        s16x4 pk;
#pragma unroll
        for (int r = 0; r < 4; r++) pk[r] = f2b(acc[i][jj][r]);
        size_t ob = ((size_t)((b * 8 + hh) * 64 + d)) * 1024 + s_base + i * 16;
        *(s16x4*)(Vt + ob) = pk;
      }
  }
}

// ---------------- causal flash attention, 1 wave / 16 q-rows ----------------
// Qa,Ka: (bh, s, 64) bf16 (Q pre-scaled by 0.125*log2e); Vt: (bh, 64, 1024) bf16
// O: [b*1024+q][h*64+d] bf16
__global__ __launch_bounds__(64) void k_attn(const short* __restrict__ Qb,
                                             const short* __restrict__ Kb,
                                             const short* __restrict__ Vt,
                                             short* __restrict__ O){
  __shared__ __align__(16) short myP[16 * 72];
  const int bh = blockIdx.y;
  const int qt = 63 - blockIdx.x;            // heavy tiles first
  const int lane = threadIdx.x;
  const int fr = lane & 15, fg = lane >> 4;
  const int qw = qt * 16;
  const short* Qp = Qb + (size_t)bh * 65536;
  const short* Kp = Kb + (size_t)bh * 65536;
  const short* Vp = Vt + (size_t)bh * 65536;

  s16x8 qf0 = *(const s16x8*)(Qp + (size_t)(qw + fr) * 64 + fg * 8);
  s16x8 qf1 = *(const s16x8*)(Qp + (size_t)(qw + fr) * 64 + 32 + fg * 8);

  f32x4 oacc[4] = {};
  float mrun = -1e30f, lrun = 0.f;

  for (int kv0 = 0; kv0 <= qw; kv0 += 64){
    // ---- scores (swapped): D[kv][q], row=kv_local=fg*4+r, col=q_local=fr ----
    f32x4 sc[4];
#pragma unroll
    for (int f = 0; f < 4; f++){
      s16x8 kf0 = *(const s16x8*)(Kp + (size_t)(kv0 + f * 16 + fr) * 64 + fg * 8);
      s16x8 kf1 = *(const s16x8*)(Kp + (size_t)(kv0 + f * 16 + fr) * 64 + 32 + fg * 8);
      f32x4 s = {};
      s = __builtin_amdgcn_mfma_f32_16x16x32_bf16(as_bf(kf0), as_bf(qf0), s, 0, 0, 0);
      s = __builtin_amdgcn_mfma_f32_16x16x32_bf16(as_bf(kf1), as_bf(qf1), s, 0, 0, 0);
      sc[f] = s;
    }
    const int q = qw + fr;                   // this lane's q-row (softmax axis)
    if (kv0 + 63 > qw){
#pragma unroll
      for (int f = 0; f < 4; f++)
#pragma unroll
        for (int r = 0; r < 4; r++){
          int kv = kv0 + f * 16 + fg * 4 + r;
          if (kv > q) sc[f][r] = -1e30f;
        }
    }
    // ---- online softmax: per-lane over 16 regs, then 2 shfl over fg ----
    float tmax = -1e30f;
#pragma unroll
    for (int f = 0; f < 4; f++)
#pragma unroll
      for (int r = 0; r < 4; r++) tmax = fmaxf(tmax, sc[f][r]);
    tmax = fmaxf(tmax, __shfl_xor(tmax, 16, 64));
    tmax = fmaxf(tmax, __shfl_xor(tmax, 32, 64));
    float mnew = fmaxf(mrun, tmax);
    float corr = fexp2(mrun - mnew);         // scores are in log2-e domain
    mrun = mnew;
    float rs = 0.f;
    s16x4 pb[4];
#pragma unroll
    for (int f = 0; f < 4; f++)
#pragma unroll
      for (int r = 0; r < 4; r++){
        float p = fexp2(sc[f][r] - mnew);
        rs += p;
        pb[f][r] = f2b(p);
      }
    rs += __shfl_xor(rs, 16, 64);
    rs += __shfl_xor(rs, 32, 64);
    lrun = lrun * corr + rs;
    // ---- write P^T to LDS as P[q][kv] (vector 8B writes), read A-frags ----
#pragma unroll
    for (int f = 0; f < 4; f++)
      *(s16x4*)(&myP[fr * 72 + f * 16 + fg * 4]) = pb[f];
    s16x8 pa0 = *(const s16x8*)(&myP[fr * 72 + fg * 8]);
    s16x8 pa1 = *(const s16x8*)(&myP[fr * 72 + 32 + fg * 8]);
    // ---- rescale O (PV layout: q_local = fg*4+r) ----
    float cpv[4];
#pragma unroll
    for (int r = 0; r < 4; r++) cpv[r] = __shfl(corr, fg * 4 + r, 64);
#pragma unroll
    for (int jj = 0; jj < 4; jj++)
#pragma unroll
      for (int r = 0; r < 4; r++) oacc[jj][r] *= cpv[r];
    // ---- O += P V ----
#pragma unroll
    for (int jj = 0; jj < 4; jj++){
      s16x8 vf0 = *(const s16x8*)(Vp + (size_t)(jj * 16 + fr) * 1024 + kv0 + fg * 8);
      s16x8 vf1 = *(const s16x8*)(Vp + (size_t)(jj * 16 + fr) * 1024 + kv0 + 32 + fg * 8);
      oacc[jj] = __builtin_amdgcn_mfma_f32_16x16x32_bf16(as_bf(pa0), as_bf(vf0), oacc[jj], 0, 0, 0);
      oacc[jj] = __builtin_amdgcn_mfma_f32_16x16x32_bf16(as_bf(pa1), as_bf(vf1), oacc[jj], 0, 0, 0);
    }
  }
  float lpv[4];
#pragma unroll
  for (int r = 0; r < 4; r++) lpv[r] = __shfl(lrun, fg * 4 + r, 64);
  const int b = bh >> 3, h = bh & 7;
#pragma unroll
  for (int jj = 0; jj < 4; jj++)
#pragma unroll
    for (int r = 0; r < 4; r++){
      int qq = qw + fg * 4 + r;
      O[(size_t)(b * 1024 + qq) * 512 + h * 64 + jj * 16 + fr] = f2b(oacc[jj][r] / lpv[r]);
    }
}

// ---------------- final GEMM: f32 out ----------------
__global__ __launch_bounds__(256) void k_gemm_out(const short* __restrict__ X,
                                                  const short* __restrict__ Wt,
                                                  float* __restrict__ C){
  __shared__ __align__(16) short Al[128 * 32];
  __shared__ __align__(16) short Bl[128 * 32];
  const int t = threadIdx.x;
  const int w = t >> 6, lane = t & 63, fr = lane & 15, fg = lane >> 4;
  const int bm = blockIdx.x * 128, bn = blockIdx.y * 128;
  const int wm = (w >> 1) * 64, wn = (w & 1) * 64;
  const int r8 = t >> 2, c8 = (t & 3) * 8;
  f32x4 acc[4][4] = {};
  for (int k0 = 0; k0 < 512; k0 += 32){
    __syncthreads();
#pragma unroll
    for (int j = 0; j < 2; j++){
      const short* ga = X  + (size_t)(bm + j * 64 + r8) * 512 + (k0 + c8);
      const short* gb = Wt + (size_t)(bn + j * 64 + r8) * 512 + (k0 + c8);
      gload_lds16(ga, &Al[j * 2048 + w * 512]);
      gload_lds16(gb, &Bl[j * 2048 + w * 512]);
    }
    __syncthreads();
    s16x8 af[4], bv[4];
#pragma unroll
    for (int f = 0; f < 4; f++){
      af[f] = *(const s16x8*)(&Al[(wm + f * 16 + fr) * 32 + fg * 8]);
      bv[f] = *(const s16x8*)(&Bl[(wn + f * 16 + fr) * 32 + fg * 8]);
    }
#pragma unroll
    for (int i = 0; i < 4; i++)
#pragma unroll
      for (int jj = 0; jj < 4; jj++)
        acc[i][jj] = __builtin_amdgcn_mfma_f32_16x16x32_bf16(as_bf(af[i]), as_bf(bv[jj]),
                                                             acc[i][jj], 0, 0, 0);
  }
  const int row0 = bm + wm + fg * 4;
  const int col0 = bn + wn + fr;
#pragma unroll
  for (int i = 0; i < 4; i++)
#pragma unroll
    for (int jj = 0; jj < 4; jj++)
#pragma unroll
      for (int r = 0; r < 4; r++)
        C[(size_t)(row0 + i * 16 + r) * 512 + col0 + jj * 16] = acc[i][jj][r];
}

extern "C" void kernel_launch(void* const* d_in, const int* in_sizes, int n_in,
                              void* d_out, int out_size, void* d_ws, size_t ws_size,
                              hipStream_t stream){
  const float* query  = (const float*)d_in[0];
  const float* value  = (const float*)d_in[1];
  const float* key_in = (const float*)d_in[2];
  const float* Wq     = (const float*)d_in[3];
  const float* Wk     = (const float*)d_in[4];
  const float* Wv     = (const float*)d_in[5];
  const float* Wo     = (const float*)d_in[6];

  char* ws = (char*)d_ws;
  const size_t MB = 1ull << 20;
  short* Xq   = (short*)(ws);                    // 8 MB  (later reused as O)
  short* Xk   = (short*)(ws + 8 * MB);           // 8 MB
  short* Xv   = (short*)(ws + 16 * MB);          // 8 MB
  short* Wcat = (short*)(ws + 24 * MB);          // 2 MB: Wq,Wk,Wv,Wo transposed
  float* tab  = (float*)(ws + 26 * MB);          // 256 KB
  short* Qa   = (short*)(ws + 26 * MB + 256 * 1024);   // 8 MB
  short* Ka   = (short*)((char*)Qa + 8 * MB);          // 8 MB
  short* Va   = (short*)((char*)Ka + 8 * MB);          // 8 MB  (ends at 50.25 MB)
  short* Oa   = Xq;
  short* Wot  = Wcat + 786432;                   // Wo^T block

  k_conv3<<<dim3(4096, 1, 3), 256, 0, stream>>>(query, key_in, value, Xq);
  k_wt4<<<dim3(16, 16, 4), dim3(32, 8), 0, stream>>>(Wq, Wk, Wv, Wo, Wcat);
  k_table<<<128, 256, 0, stream>>>(tab);

  k_qkv<<<dim3(64, 12), 256, 0, stream>>>(Xq, Xk, Xv, Wcat, tab, Qa, Ka, Va);

  k_attn<<<dim3(64, 64), 64, 0, stream>>>(Qa, Ka, Va, Oa);

  k_gemm_out<<<dim3(64, 4), 256, 0, stream>>>(Oa, Wot, (float*)d_out);
}

// Round 4
// 123.618 us; speedup vs baseline: 1.7569x; 1.2844x over previous
//
#include <hip/hip_runtime.h>
#include <hip/hip_bf16.h>
#include <stdint.h>

#define DEV static __device__ __forceinline__

typedef __attribute__((ext_vector_type(8))) short   s16x8;
typedef __attribute__((ext_vector_type(4))) short   s16x4;
typedef __attribute__((ext_vector_type(8))) __bf16  bf16x8;
typedef __attribute__((ext_vector_type(4))) float   f32x4;

DEV short f2b(float f){           // round-to-nearest-even f32 -> bf16
  union{float f; uint32_t i;} x; x.f = f;
  uint32_t r = x.i + 0x7FFFu + ((x.i >> 16) & 1u);
  return (short)(r >> 16);
}
DEV bf16x8 as_bf(s16x8 v){ return __builtin_bit_cast(bf16x8, v); }
DEV float fexp2(float x){ return __builtin_amdgcn_exp2f(x); }   // v_exp_f32: 2^x
DEV f32x4 mf(s16x8 a, s16x8 b, f32x4 c){
  return __builtin_amdgcn_mfma_f32_16x16x32_bf16(as_bf(a), as_bf(b), c, 0, 0, 0);
}

DEV void gload_lds16(const void* g, void* l){
  __builtin_amdgcn_global_load_lds((const __attribute__((address_space(1))) void*)g,
                                   (__attribute__((address_space(3))) void*)l, 16, 0, 0);
}

// ---------------- fused convert f32 -> bf16 for query/key_in/value ----------------
__global__ __launch_bounds__(256) void k_conv3(const float* __restrict__ q,
                                               const float* __restrict__ k,
                                               const float* __restrict__ v,
                                               short* __restrict__ out){
  int z = blockIdx.z;
  const float* in = (z == 0) ? q : (z == 1) ? k : v;
  int i = (blockIdx.x * 256 + threadIdx.x) * 4;
  float4 val = *(const float4*)(in + i);
  short o[4] = { f2b(val.x), f2b(val.y), f2b(val.z), f2b(val.w) };
  *(uint2*)(out + (size_t)z * 4194304 + i) = *(uint2*)o;
}

// ------------- fused weight transpose+convert: 4x w[512][512] f32 -> wt[n][k] bf16 -------------
__global__ __launch_bounds__(256) void k_wt4(const float* __restrict__ w0,
                                             const float* __restrict__ w1,
                                             const float* __restrict__ w2,
                                             const float* __restrict__ w3,
                                             short* __restrict__ wt){
  __shared__ float tile[32][33];
  int z = blockIdx.z;
  const float* w = (z == 0) ? w0 : (z == 1) ? w1 : (z == 2) ? w2 : w3;
  short* o = wt + (size_t)z * 262144;
  int bx = blockIdx.x * 32, by = blockIdx.y * 32;   // bx: n-block, by: k-block
  int tx = threadIdx.x, ty = threadIdx.y;           // (32, 8)
  for (int j = 0; j < 32; j += 8)
    tile[ty + j][tx] = w[(size_t)(by + ty + j) * 512 + bx + tx];
  __syncthreads();
  for (int j = 0; j < 32; j += 8)
    o[(size_t)(bx + ty + j) * 512 + by + tx] = f2b(tile[tx][ty + j]);
}

// ---------------- RoPE cos/sin table: tab[s][j][{cos,sin}], s<1024, j<32 ----------------
__global__ __launch_bounds__(256) void k_table(float* __restrict__ tab){
  int idx = blockIdx.x * 256 + threadIdx.x;   // 32768
  int s = idx >> 5, j = idx & 31;
  float inv = __expf(-(float)j * (1.0f / 32.0f) * logf(10000.0f));
  float ang = (float)s * inv;
  tab[idx * 2 + 0] = cosf(ang);
  tab[idx * 2 + 1] = sinf(ang);
}

// ---------------- fused QKV GEMM + RoPE/layout epilogues ----------------
__global__ __launch_bounds__(256) void k_qkv(const short* __restrict__ Xq,
                                             const short* __restrict__ Xk,
                                             const short* __restrict__ Xv,
                                             const short* __restrict__ Wcat,
                                             const float* __restrict__ tab,
                                             short* __restrict__ Qa,
                                             short* __restrict__ Ka,
                                             short* __restrict__ Vt){
  __shared__ __align__(16) short Al[128 * 32];
  __shared__ __align__(16) short Bl[128 * 32];
  const int t = threadIdx.x;
  const int w = t >> 6, lane = t & 63, fr = lane & 15, fg = lane >> 4;
  const int sel = blockIdx.y >> 2;
  const short* X = (sel == 0) ? Xq : (sel == 1) ? Xk : Xv;
  const int bm = blockIdx.x * 128, bn = blockIdx.y * 128;
  const int wm = (w >> 1) * 64, wn = (w & 1) * 64;
  const int r8 = t >> 2, c8 = (t & 3) * 8;
  f32x4 acc[4][4] = {};
  for (int k0 = 0; k0 < 512; k0 += 32){
    __syncthreads();
#pragma unroll
    for (int j = 0; j < 2; j++){
      const short* ga = X    + (size_t)(bm + j * 64 + r8) * 512 + (k0 + c8);
      const short* gb = Wcat + (size_t)(bn + j * 64 + r8) * 512 + (k0 + c8);
      gload_lds16(ga, &Al[j * 2048 + w * 512]);
      gload_lds16(gb, &Bl[j * 2048 + w * 512]);
    }
    __syncthreads();
    s16x8 af[4], bv[4];
#pragma unroll
    for (int f = 0; f < 4; f++){
      af[f] = *(const s16x8*)(&Al[(wm + f * 16 + fr) * 32 + fg * 8]);
      bv[f] = *(const s16x8*)(&Bl[(wn + f * 16 + fr) * 32 + fg * 8]);
    }
#pragma unroll
    for (int i = 0; i < 4; i++)
#pragma unroll
      for (int jj = 0; jj < 4; jj++)
        acc[i][jj] = __builtin_amdgcn_mfma_f32_16x16x32_bf16(as_bf(af[i]), as_bf(bv[jj]),
                                                             acc[i][jj], 0, 0, 0);
  }
  const int row0 = bm + wm + fg * 4;         // + i*16 + r
  const int b = row0 >> 10;
  const int s_base = row0 & 1023;
  const int hh = (((blockIdx.y & 3) * 128) + wn) >> 6;   // head 0..7
  if (sel < 2){
    const float scale = (sel == 0) ? 0.125f * 1.44269504f : 1.0f;
    short* out = (sel == 0) ? Qa : Ka;
#pragma unroll
    for (int i = 0; i < 4; i++)
#pragma unroll
      for (int jj = 0; jj < 2; jj++){
        int d = jj * 16 + fr;                // 0..31
#pragma unroll
        for (int r = 0; r < 4; r++){
          int s = s_base + i * 16 + r;
          float2 cs = *(const float2*)(tab + (size_t)(s * 32 + d) * 2);
          float x1 = acc[i][jj][r], x2 = acc[i][jj + 2][r];
          size_t ob = ((size_t)((b * 8 + hh) * 1024 + s)) * 64 + d;
          out[ob]      = f2b((x1 * cs.x - x2 * cs.y) * scale);
          out[ob + 32] = f2b((x2 * cs.x + x1 * cs.y) * scale);
        }
      }
  } else {
#pragma unroll
    for (int i = 0; i < 4; i++)
#pragma unroll
      for (int jj = 0; jj < 4; jj++){
        int d = jj * 16 + fr;
        s16x4 pk;
#pragma unroll
        for (int r = 0; r < 4; r++) pk[r] = f2b(acc[i][jj][r]);
        size_t ob = ((size_t)((b * 8 + hh) * 64 + d)) * 1024 + s_base + i * 16;
        *(s16x4*)(Vt + ob) = pk;
      }
  }
}

// ---- softmax prep: per-lane 16 scores for q=fr, reduce over fg, pack P to LDS, read A-frags ----
DEV void sm_prep(f32x4 (&sc)[4], float& mrun, float& lrun, short* P, int fr, int fg,
                 s16x8& pa0, s16x8& pa1, float& corr){
  float tmax = -1e30f;
#pragma unroll
  for (int f = 0; f < 4; f++)
#pragma unroll
    for (int r = 0; r < 4; r++) tmax = fmaxf(tmax, sc[f][r]);
  tmax = fmaxf(tmax, __shfl_xor(tmax, 16, 64));
  tmax = fmaxf(tmax, __shfl_xor(tmax, 32, 64));
  float mnew = fmaxf(mrun, tmax);
  corr = fexp2(mrun - mnew);
  mrun = mnew;
  float rs = 0.f;
  s16x4 pb[4];
#pragma unroll
  for (int f = 0; f < 4; f++)
#pragma unroll
    for (int r = 0; r < 4; r++){
      float p = fexp2(sc[f][r] - mnew);
      rs += p;
      pb[f][r] = f2b(p);
    }
  rs += __shfl_xor(rs, 16, 64);
  rs += __shfl_xor(rs, 32, 64);
  lrun = lrun * corr + rs;
#pragma unroll
  for (int f = 0; f < 4; f++)
    *(s16x4*)(&P[fr * 72 + f * 16 + fg * 4]) = pb[f];
  pa0 = *(const s16x8*)(&P[fr * 72 + fg * 8]);
  pa1 = *(const s16x8*)(&P[fr * 72 + 32 + fg * 8]);
}

// ---------------- causal flash attention: paired q-tiles (p, 63-p), 1 wave/block ----------------
// Qa,Ka: (bh, s, 64) bf16 (Q pre-scaled by 0.125*log2e); Vt: (bh, 64, 1024) bf16
// O: [b*1024+q][h*64+d] bf16.  2048 blocks, constant 17 tile-computations each.
__global__ __launch_bounds__(64) void k_attn(const short* __restrict__ Qb,
                                             const short* __restrict__ Kb,
                                             const short* __restrict__ Vt,
                                             short* __restrict__ O){
  __shared__ __align__(16) short PA[16 * 72];
  __shared__ __align__(16) short PB[16 * 72];
  const int gid = blockIdx.x;
  const int swz = (gid & 7) * 256 + (gid >> 3);   // XCD-contiguous bh chunks
  const int bh  = swz >> 5;                        // 0..63
  const int pr  = swz & 31;                        // 0..31
  const int qwA = pr * 16;
  const int qwB = (63 - pr) * 16;
  const int lane = threadIdx.x, fr = lane & 15, fg = lane >> 4;
  const short* Qp = Qb + (size_t)bh * 65536;
  const short* Kp = Kb + (size_t)bh * 65536;
  const short* Vp = Vt + (size_t)bh * 65536;

  s16x8 qA0 = *(const s16x8*)(Qp + (size_t)(qwA + fr) * 64 + fg * 8);
  s16x8 qA1 = *(const s16x8*)(Qp + (size_t)(qwA + fr) * 64 + 32 + fg * 8);
  s16x8 qB0 = *(const s16x8*)(Qp + (size_t)(qwB + fr) * 64 + fg * 8);
  s16x8 qB1 = *(const s16x8*)(Qp + (size_t)(qwB + fr) * 64 + 32 + fg * 8);

  f32x4 oA[4] = {}, oB[4] = {};
  float mA = -1e30f, lA = 0.f, mB = -1e30f, lB = 0.f;

  s16x8 kc0[4], kc1[4], kn0[4], kn1[4];
#pragma unroll
  for (int f = 0; f < 4; f++){
    kc0[f] = *(const s16x8*)(Kp + (size_t)(f * 16 + fr) * 64 + fg * 8);
    kc1[f] = *(const s16x8*)(Kp + (size_t)(f * 16 + fr) * 64 + 32 + fg * 8);
  }

  auto body = [&](s16x8 (&c0)[4], s16x8 (&c1)[4], s16x8 (&n0)[4], s16x8 (&n1)[4], int kv0){
    const bool Aact = (kv0 <= qwA);
    // ---- QK^T (swapped): D[kv][q] for both tiles off the same K frags ----
    f32x4 sB[4], sA[4];
#pragma unroll
    for (int f = 0; f < 4; f++){
      f32x4 s = {};
      s = mf(c0[f], qB0, s); s = mf(c1[f], qB1, s);
      sB[f] = s;
    }
    if (Aact){
#pragma unroll
      for (int f = 0; f < 4; f++){
        f32x4 s = {};
        s = mf(c0[f], qA0, s); s = mf(c1[f], qA1, s);
        sA[f] = s;
      }
    }
    // ---- V loads early (softmax VALU hides them); shared by both tiles ----
    s16x8 v0[4], v1[4];
#pragma unroll
    for (int jj = 0; jj < 4; jj++){
      v0[jj] = *(const s16x8*)(Vp + (size_t)(jj * 16 + fr) * 1024 + kv0 + fg * 8);
      v1[jj] = *(const s16x8*)(Vp + (size_t)(jj * 16 + fr) * 1024 + kv0 + 32 + fg * 8);
    }
    // ---- prefetch next K tile into the role-swapped register set ----
    const int nkv = kv0 + 64;
    if (nkv <= qwB){
#pragma unroll
      for (int f = 0; f < 4; f++){
        n0[f] = *(const s16x8*)(Kp + (size_t)(nkv + f * 16 + fr) * 64 + fg * 8);
        n1[f] = *(const s16x8*)(Kp + (size_t)(nkv + f * 16 + fr) * 64 + 32 + fg * 8);
      }
    }
    // ---- causal masks (diagonal tiles only) ----
    if (kv0 + 63 > qwB){
      int q = qwB + fr;
#pragma unroll
      for (int f = 0; f < 4; f++)
#pragma unroll
        for (int r = 0; r < 4; r++){
          int kv = kv0 + f * 16 + fg * 4 + r;
          if (kv > q) sB[f][r] = -1e30f;
        }
    }
    if (Aact && kv0 + 63 > qwA){
      int q = qwA + fr;
#pragma unroll
      for (int f = 0; f < 4; f++)
#pragma unroll
        for (int r = 0; r < 4; r++){
          int kv = kv0 + f * 16 + fg * 4 + r;
          if (kv > q) sA[f][r] = -1e30f;
        }
    }
    // ---- two independent softmax chains (ILP) ----
    s16x8 paB0, paB1, paA0, paA1;
    float cB, cA;
    sm_prep(sB, mB, lB, PB, fr, fg, paB0, paB1, cB);
    if (Aact) sm_prep(sA, mA, lA, PA, fr, fg, paA0, paA1, cA);
    // ---- rescale O (PV layout: q_local = fg*4+r) ----
    float cpv[4];
#pragma unroll
    for (int r = 0; r < 4; r++) cpv[r] = __shfl(cB, fg * 4 + r, 64);
#pragma unroll
    for (int jj = 0; jj < 4; jj++)
#pragma unroll
      for (int r = 0; r < 4; r++) oB[jj][r] *= cpv[r];
    if (Aact){
#pragma unroll
      for (int r = 0; r < 4; r++) cpv[r] = __shfl(cA, fg * 4 + r, 64);
#pragma unroll
      for (int jj = 0; jj < 4; jj++)
#pragma unroll
        for (int r = 0; r < 4; r++) oA[jj][r] *= cpv[r];
    }
    // ---- PV: one V-frag set feeds both tiles ----
#pragma unroll
    for (int jj = 0; jj < 4; jj++){
      oB[jj] = mf(paB0, v0[jj], oB[jj]);
      oB[jj] = mf(paB1, v1[jj], oB[jj]);
    }
    if (Aact){
#pragma unroll
      for (int jj = 0; jj < 4; jj++){
        oA[jj] = mf(paA0, v0[jj], oA[jj]);
        oA[jj] = mf(paA1, v1[jj], oA[jj]);
      }
    }
  };

  int kv0 = 0;
  while (true){
    body(kc0, kc1, kn0, kn1, kv0); kv0 += 64; if (kv0 > qwB) break;
    body(kn0, kn1, kc0, kc1, kv0); kv0 += 64; if (kv0 > qwB) break;
  }

  const int b = bh >> 3, h = bh & 7;
  float lpv[4];
#pragma unroll
  for (int r = 0; r < 4; r++) lpv[r] = __shfl(lB, fg * 4 + r, 64);
#pragma unroll
  for (int jj = 0; jj < 4; jj++)
#pragma unroll
    for (int r = 0; r < 4; r++){
      int qq = qwB + fg * 4 + r;
      O[(size_t)(b * 1024 + qq) * 512 + h * 64 + jj * 16 + fr] = f2b(oB[jj][r] / lpv[r]);
    }
#pragma unroll
  for (int r = 0; r < 4; r++) lpv[r] = __shfl(lA, fg * 4 + r, 64);
#pragma unroll
  for (int jj = 0; jj < 4; jj++)
#pragma unroll
    for (int r = 0; r < 4; r++){
      int qq = qwA + fg * 4 + r;
      O[(size_t)(b * 1024 + qq) * 512 + h * 64 + jj * 16 + fr] = f2b(oA[jj][r] / lpv[r]);
    }
}

// ---------------- final GEMM: f32 out ----------------
__global__ __launch_bounds__(256) void k_gemm_out(const short* __restrict__ X,
                                                  const short* __restrict__ Wt,
                                                  float* __restrict__ C){
  __shared__ __align__(16) short Al[128 * 32];
  __shared__ __align__(16) short Bl[128 * 32];
  const int t = threadIdx.x;
  const int w = t >> 6, lane = t & 63, fr = lane & 15, fg = lane >> 4;
  const int bm = blockIdx.x * 128, bn = blockIdx.y * 128;
  const int wm = (w >> 1) * 64, wn = (w & 1) * 64;
  const int r8 = t >> 2, c8 = (t & 3) * 8;
  f32x4 acc[4][4] = {};
  for (int k0 = 0; k0 < 512; k0 += 32){
    __syncthreads();
#pragma unroll
    for (int j = 0; j < 2; j++){
      const short* ga = X  + (size_t)(bm + j * 64 + r8) * 512 + (k0 + c8);
      const short* gb = Wt + (size_t)(bn + j * 64 + r8) * 512 + (k0 + c8);
      gload_lds16(ga, &Al[j * 2048 + w * 512]);
      gload_lds16(gb, &Bl[j * 2048 + w * 512]);
    }
    __syncthreads();
    s16x8 af[4], bv[4];
#pragma unroll
    for (int f = 0; f < 4; f++){
      af[f] = *(const s16x8*)(&Al[(wm + f * 16 + fr) * 32 + fg * 8]);
      bv[f] = *(const s16x8*)(&Bl[(wn + f * 16 + fr) * 32 + fg * 8]);
    }
#pragma unroll
    for (int i = 0; i < 4; i++)
#pragma unroll
      for (int jj = 0; jj < 4; jj++)
        acc[i][jj] = __builtin_amdgcn_mfma_f32_16x16x32_bf16(as_bf(af[i]), as_bf(bv[jj]),
                                                             acc[i][jj], 0, 0, 0);
  }
  const int row0 = bm + wm + fg * 4;
  const int col0 = bn + wn + fr;
#pragma unroll
  for (int i = 0; i < 4; i++)
#pragma unroll
    for (int jj = 0; jj < 4; jj++)
#pragma unroll
      for (int r = 0; r < 4; r++)
        C[(size_t)(row0 + i * 16 + r) * 512 + col0 + jj * 16] = acc[i][jj][r];
}

extern "C" void kernel_launch(void* const* d_in, const int* in_sizes, int n_in,
                              void* d_out, int out_size, void* d_ws, size_t ws_size,
                              hipStream_t stream){
  const float* query  = (const float*)d_in[0];
  const float* value  = (const float*)d_in[1];
  const float* key_in = (const float*)d_in[2];
  const float* Wq     = (const float*)d_in[3];
  const float* Wk     = (const float*)d_in[4];
  const float* Wv     = (const float*)d_in[5];
  const float* Wo     = (const float*)d_in[6];

  char* ws = (char*)d_ws;
  const size_t MB = 1ull << 20;
  short* Xq   = (short*)(ws);                    // 8 MB  (later reused as O)
  short* Xk   = (short*)(ws + 8 * MB);           // 8 MB
  short* Xv   = (short*)(ws + 16 * MB);          // 8 MB
  short* Wcat = (short*)(ws + 24 * MB);          // 2 MB: Wq,Wk,Wv,Wo transposed
  float* tab  = (float*)(ws + 26 * MB);          // 256 KB
  short* Qa   = (short*)(ws + 26 * MB + 256 * 1024);   // 8 MB
  short* Ka   = (short*)((char*)Qa + 8 * MB);          // 8 MB
  short* Va   = (short*)((char*)Ka + 8 * MB);          // 8 MB  (ends at 50.25 MB)
  short* Oa   = Xq;
  short* Wot  = Wcat + 786432;                   // Wo^T block

  k_conv3<<<dim3(4096, 1, 3), 256, 0, stream>>>(query, key_in, value, Xq);
  k_wt4<<<dim3(16, 16, 4), dim3(32, 8), 0, stream>>>(Wq, Wk, Wv, Wo, Wcat);
  k_table<<<128, 256, 0, stream>>>(tab);

  k_qkv<<<dim3(64, 12), 256, 0, stream>>>(Xq, Xk, Xv, Wcat, tab, Qa, Ka, Va);

  k_attn<<<2048, 64, 0, stream>>>(Qa, Ka, Va, Oa);

  k_gemm_out<<<dim3(64, 4), 256, 0, stream>>>(Oa, Wot, (float*)d_out);
}

// Round 5
// 123.076 us; speedup vs baseline: 1.7646x; 1.0044x over previous
//
#include <hip/hip_runtime.h>
#include <hip/hip_bf16.h>
#include <stdint.h>

#define DEV static __device__ __forceinline__

typedef __attribute__((ext_vector_type(8))) short   s16x8;
typedef __attribute__((ext_vector_type(4))) short   s16x4;
typedef __attribute__((ext_vector_type(8))) __bf16  bf16x8;
typedef __attribute__((ext_vector_type(4))) float   f32x4;

DEV short f2b(float f){           // round-to-nearest-even f32 -> bf16
  union{float f; uint32_t i;} x; x.f = f;
  uint32_t r = x.i + 0x7FFFu + ((x.i >> 16) & 1u);
  return (short)(r >> 16);
}
DEV bf16x8 as_bf(s16x8 v){ return __builtin_bit_cast(bf16x8, v); }
DEV float fexp2(float x){ return __builtin_amdgcn_exp2f(x); }   // v_exp_f32: 2^x
DEV f32x4 mf(s16x8 a, s16x8 b, f32x4 c){
  return __builtin_amdgcn_mfma_f32_16x16x32_bf16(as_bf(a), as_bf(b), c, 0, 0, 0);
}

DEV void gload_lds16(const void* g, void* l){
  __builtin_amdgcn_global_load_lds((const __attribute__((address_space(1))) void*)g,
                                   (__attribute__((address_space(3))) void*)l, 16, 0, 0);
}

// ---------------- fused convert f32 -> bf16 for query/key_in/value ----------------
__global__ __launch_bounds__(256) void k_conv3(const float* __restrict__ q,
                                               const float* __restrict__ k,
                                               const float* __restrict__ v,
                                               short* __restrict__ out){
  int z = blockIdx.z;
  const float* in = (z == 0) ? q : (z == 1) ? k : v;
  int i = (blockIdx.x * 256 + threadIdx.x) * 4;
  float4 val = *(const float4*)(in + i);
  short o[4] = { f2b(val.x), f2b(val.y), f2b(val.z), f2b(val.w) };
  *(uint2*)(out + (size_t)z * 4194304 + i) = *(uint2*)o;
}

// ------------- fused weight transpose+convert: 4x w[512][512] f32 -> wt[n][k] bf16 -------------
__global__ __launch_bounds__(256) void k_wt4(const float* __restrict__ w0,
                                             const float* __restrict__ w1,
                                             const float* __restrict__ w2,
                                             const float* __restrict__ w3,
                                             short* __restrict__ wt){
  __shared__ float tile[32][33];
  int z = blockIdx.z;
  const float* w = (z == 0) ? w0 : (z == 1) ? w1 : (z == 2) ? w2 : w3;
  short* o = wt + (size_t)z * 262144;
  int bx = blockIdx.x * 32, by = blockIdx.y * 32;   // bx: n-block, by: k-block
  int tx = threadIdx.x, ty = threadIdx.y;           // (32, 8)
  for (int j = 0; j < 32; j += 8)
    tile[ty + j][tx] = w[(size_t)(by + ty + j) * 512 + bx + tx];
  __syncthreads();
  for (int j = 0; j < 32; j += 8)
    o[(size_t)(bx + ty + j) * 512 + by + tx] = f2b(tile[tx][ty + j]);
}

// ---------------- RoPE cos/sin table: tab[s][j][{cos,sin}], s<1024, j<32 ----------------
__global__ __launch_bounds__(256) void k_table(float* __restrict__ tab){
  int idx = blockIdx.x * 256 + threadIdx.x;   // 32768
  int s = idx >> 5, j = idx & 31;
  float inv = __expf(-(float)j * (1.0f / 32.0f) * logf(10000.0f));
  float ang = (float)s * inv;
  tab[idx * 2 + 0] = cosf(ang);
  tab[idx * 2 + 1] = sinf(ang);
}

// ---------------- fused QKV GEMM + RoPE/layout epilogues ----------------
__global__ __launch_bounds__(256) void k_qkv(const short* __restrict__ Xq,
                                             const short* __restrict__ Xk,
                                             const short* __restrict__ Xv,
                                             const short* __restrict__ Wcat,
                                             const float* __restrict__ tab,
                                             short* __restrict__ Qa,
                                             short* __restrict__ Ka,
                                             short* __restrict__ Vt){
  __shared__ __align__(16) short Al[128 * 32];
  __shared__ __align__(16) short Bl[128 * 32];
  const int t = threadIdx.x;
  const int w = t >> 6, lane = t & 63, fr = lane & 15, fg = lane >> 4;
  const int sel = blockIdx.y >> 2;
  const short* X = (sel == 0) ? Xq : (sel == 1) ? Xk : Xv;
  const int bm = blockIdx.x * 128, bn = blockIdx.y * 128;
  const int wm = (w >> 1) * 64, wn = (w & 1) * 64;
  const int r8 = t >> 2, c8 = (t & 3) * 8;
  f32x4 acc[4][4] = {};
  for (int k0 = 0; k0 < 512; k0 += 32){
    __syncthreads();
#pragma unroll
    for (int j = 0; j < 2; j++){
      const short* ga = X    + (size_t)(bm + j * 64 + r8) * 512 + (k0 + c8);
      const short* gb = Wcat + (size_t)(bn + j * 64 + r8) * 512 + (k0 + c8);
      gload_lds16(ga, &Al[j * 2048 + w * 512]);
      gload_lds16(gb, &Bl[j * 2048 + w * 512]);
    }
    __syncthreads();
    s16x8 af[4], bv[4];
#pragma unroll
    for (int f = 0; f < 4; f++){
      af[f] = *(const s16x8*)(&Al[(wm + f * 16 + fr) * 32 + fg * 8]);
      bv[f] = *(const s16x8*)(&Bl[(wn + f * 16 + fr) * 32 + fg * 8]);
    }
#pragma unroll
    for (int i = 0; i < 4; i++)
#pragma unroll
      for (int jj = 0; jj < 4; jj++)
        acc[i][jj] = __builtin_amdgcn_mfma_f32_16x16x32_bf16(as_bf(af[i]), as_bf(bv[jj]),
                                                             acc[i][jj], 0, 0, 0);
  }
  const int row0 = bm + wm + fg * 4;         // + i*16 + r
  const int b = row0 >> 10;
  const int s_base = row0 & 1023;
  const int hh = (((blockIdx.y & 3) * 128) + wn) >> 6;   // head 0..7
  if (sel < 2){
    const float scale = (sel == 0) ? 0.125f * 1.44269504f : 1.0f;
    short* out = (sel == 0) ? Qa : Ka;
#pragma unroll
    for (int i = 0; i < 4; i++)
#pragma unroll
      for (int jj = 0; jj < 2; jj++){
        int d = jj * 16 + fr;                // 0..31
#pragma unroll
        for (int r = 0; r < 4; r++){
          int s = s_base + i * 16 + r;
          float2 cs = *(const float2*)(tab + (size_t)(s * 32 + d) * 2);
          float x1 = acc[i][jj][r], x2 = acc[i][jj + 2][r];
          size_t ob = ((size_t)((b * 8 + hh) * 1024 + s)) * 64 + d;
          out[ob]      = f2b((x1 * cs.x - x2 * cs.y) * scale);
          out[ob + 32] = f2b((x2 * cs.x + x1 * cs.y) * scale);
        }
      }
  } else {
#pragma unroll
    for (int i = 0; i < 4; i++)
#pragma unroll
      for (int jj = 0; jj < 4; jj++){
        int d = jj * 16 + fr;
        s16x4 pk;
#pragma unroll
        for (int r = 0; r < 4; r++) pk[r] = f2b(acc[i][jj][r]);
        size_t ob = ((size_t)((b * 8 + hh) * 64 + d)) * 1024 + s_base + i * 16;
        *(s16x4*)(Vt + ob) = pk;
      }
  }
}

// ---------------- causal flash attention: paired q-tiles (p, 63-p), 1 wave/block ----------------
// Software-pipelined: carries sc(i) in regs; body i computes QK(i+1) so MFMA overlaps
// the softmax(i) VALU chain.  Row-sum l accumulated via ones-column MFMA (off the chain).
// Defer-max: skip O-rescale unless the tile max exceeds running max by >8 (log2 domain).
__global__ __launch_bounds__(64) void k_attn(const short* __restrict__ Qb,
                                             const short* __restrict__ Kb,
                                             const short* __restrict__ Vt,
                                             short* __restrict__ O){
  __shared__ __align__(16) short PA[16 * 72];
  __shared__ __align__(16) short PB[16 * 72];
  const int gid = blockIdx.x;
  const int swz = (gid & 7) * 256 + (gid >> 3);   // XCD-contiguous bh chunks
  const int bh  = swz >> 5;                        // 0..63
  const int pr  = swz & 31;                        // 0..31
  const int qwA = pr * 16;
  const int qwB = (63 - pr) * 16;                  // >= 512 always
  const int lane = threadIdx.x, fr = lane & 15, fg = lane >> 4;
  const short* Qp = Qb + (size_t)bh * 65536;
  const short* Kp = Kb + (size_t)bh * 65536;
  const short* Vp = Vt + (size_t)bh * 65536;

  s16x8 qA0 = *(const s16x8*)(Qp + (size_t)(qwA + fr) * 64 + fg * 8);
  s16x8 qA1 = *(const s16x8*)(Qp + (size_t)(qwA + fr) * 64 + 32 + fg * 8);
  s16x8 qB0 = *(const s16x8*)(Qp + (size_t)(qwB + fr) * 64 + fg * 8);
  s16x8 qB1 = *(const s16x8*)(Qp + (size_t)(qwB + fr) * 64 + 32 + fg * 8);

  // ones B-fragment: column d=0 of an implicit ones-matrix (l accumulator)
  const short onev = (fr == 0) ? (short)0x3F80 : (short)0;
  s16x8 ones;
#pragma unroll
  for (int e = 0; e < 8; e++) ones[e] = onev;

  f32x4 oA[4] = {}, oB[4] = {};
  f32x4 oLA = {}, oLB = {};
  float mA = -1e30f, mB = -1e30f;

  s16x8 Kc0[4], Kc1[4], Kn0[4], Kn1[4];
#pragma unroll
  for (int f = 0; f < 4; f++){
    Kc0[f] = *(const s16x8*)(Kp + (size_t)(f * 16 + fr) * 64 + fg * 8);
    Kc1[f] = *(const s16x8*)(Kp + (size_t)(f * 16 + fr) * 64 + 32 + fg * 8);
  }
  // prologue: scores for kv0=0 (both tiles always active at kv=0)
  f32x4 scB[4], scA[4];
#pragma unroll
  for (int f = 0; f < 4; f++){
    f32x4 s = {};
    s = mf(Kc0[f], qB0, s); s = mf(Kc1[f], qB1, s);
    scB[f] = s;
  }
#pragma unroll
  for (int f = 0; f < 4; f++){
    f32x4 s = {};
    s = mf(Kc0[f], qA0, s); s = mf(Kc1[f], qA1, s);
    scA[f] = s;
  }
  // prefetch kv=64 (always exists: qwB >= 512)
#pragma unroll
  for (int f = 0; f < 4; f++){
    Kn0[f] = *(const s16x8*)(Kp + (size_t)(64 + f * 16 + fr) * 64 + fg * 8);
    Kn1[f] = *(const s16x8*)(Kp + (size_t)(64 + f * 16 + fr) * 64 + 32 + fg * 8);
  }

  auto body = [&](s16x8 (&c0)[4], s16x8 (&c1)[4], s16x8 (&n0)[4], s16x8 (&n1)[4], int kv0){
    const int nkv = kv0 + 64, pkv = kv0 + 128;
    const bool Aact = (kv0 <= qwA);
    const bool hasN = (nkv <= qwB);
    const bool AactN = (nkv <= qwA);
    // ---- V loads for this body (issued early, consumed by PV at the end) ----
    s16x8 v0[4], v1[4];
#pragma unroll
    for (int jj = 0; jj < 4; jj++){
      v0[jj] = *(const s16x8*)(Vp + (size_t)(jj * 16 + fr) * 1024 + kv0 + fg * 8);
      v1[jj] = *(const s16x8*)(Vp + (size_t)(jj * 16 + fr) * 1024 + kv0 + 32 + fg * 8);
    }
    // ---- next-body scores off prefetched K (MFMA overlaps this body's softmax) ----
    f32x4 sNB[4], sNA[4];
    if (hasN){
#pragma unroll
      for (int f = 0; f < 4; f++){
        f32x4 s = {};
        s = mf(n0[f], qB0, s); s = mf(n1[f], qB1, s);
        sNB[f] = s;
      }
      if (AactN){
#pragma unroll
        for (int f = 0; f < 4; f++){
          f32x4 s = {};
          s = mf(n0[f], qA0, s); s = mf(n1[f], qA1, s);
          sNA[f] = s;
        }
      }
    }
    // ---- prefetch K(kv0+128) into the role-swapped set ----
    if (pkv <= qwB){
#pragma unroll
      for (int f = 0; f < 4; f++){
        c0[f] = *(const s16x8*)(Kp + (size_t)(pkv + f * 16 + fr) * 64 + fg * 8);
        c1[f] = *(const s16x8*)(Kp + (size_t)(pkv + f * 16 + fr) * 64 + 32 + fg * 8);
      }
    }
    // ---- causal masks (diagonal bodies only) ----
    if (kv0 + 63 > qwB){
      int q = qwB + fr;
#pragma unroll
      for (int f = 0; f < 4; f++)
#pragma unroll
        for (int r = 0; r < 4; r++){
          int kv = kv0 + f * 16 + fg * 4 + r;
          if (kv > q) scB[f][r] = -1e30f;
        }
    }
    if (Aact && kv0 + 63 > qwA){
      int q = qwA + fr;
#pragma unroll
      for (int f = 0; f < 4; f++)
#pragma unroll
        for (int r = 0; r < 4; r++){
          int kv = kv0 + f * 16 + fg * 4 + r;
          if (kv > q) scA[f][r] = -1e30f;
        }
    }
    // ---- softmax B (defer-max) ----
    {
      float t0 = fmaxf(fmaxf(scB[0][0], scB[0][1]), fmaxf(scB[0][2], scB[0][3]));
      float t1 = fmaxf(fmaxf(scB[1][0], scB[1][1]), fmaxf(scB[1][2], scB[1][3]));
      float t2 = fmaxf(fmaxf(scB[2][0], scB[2][1]), fmaxf(scB[2][2], scB[2][3]));
      float t3 = fmaxf(fmaxf(scB[3][0], scB[3][1]), fmaxf(scB[3][2], scB[3][3]));
      float tm = fmaxf(fmaxf(t0, t1), fmaxf(t2, t3));
      tm = fmaxf(tm, __shfl_xor(tm, 16, 64));
      tm = fmaxf(tm, __shfl_xor(tm, 32, 64));
      if (!__all(tm <= mB + 8.f)){
        float mn = fmaxf(mB, tm);
        float corr = fexp2(mB - mn);
        mB = mn;
        float cpv[4];
#pragma unroll
        for (int r = 0; r < 4; r++) cpv[r] = __shfl(corr, fg * 4 + r, 64);
#pragma unroll
        for (int jj = 0; jj < 4; jj++)
#pragma unroll
          for (int r = 0; r < 4; r++) oB[jj][r] *= cpv[r];
#pragma unroll
        for (int r = 0; r < 4; r++) oLB[r] *= cpv[r];
      }
      s16x4 pb[4];
#pragma unroll
      for (int f = 0; f < 4; f++)
#pragma unroll
        for (int r = 0; r < 4; r++)
          pb[f][r] = f2b(fexp2(scB[f][r] - mB));
#pragma unroll
      for (int f = 0; f < 4; f++)
        *(s16x4*)(&PB[fr * 72 + f * 16 + fg * 4]) = pb[f];
    }
    // ---- softmax A (defer-max) ----
    if (Aact){
      float t0 = fmaxf(fmaxf(scA[0][0], scA[0][1]), fmaxf(scA[0][2], scA[0][3]));
      float t1 = fmaxf(fmaxf(scA[1][0], scA[1][1]), fmaxf(scA[1][2], scA[1][3]));
      float t2 = fmaxf(fmaxf(scA[2][0], scA[2][1]), fmaxf(scA[2][2], scA[2][3]));
      float t3 = fmaxf(fmaxf(scA[3][0], scA[3][1]), fmaxf(scA[3][2], scA[3][3]));
      float tm = fmaxf(fmaxf(t0, t1), fmaxf(t2, t3));
      tm = fmaxf(tm, __shfl_xor(tm, 16, 64));
      tm = fmaxf(tm, __shfl_xor(tm, 32, 64));
      if (!__all(tm <= mA + 8.f)){
        float mn = fmaxf(mA, tm);
        float corr = fexp2(mA - mn);
        mA = mn;
        float cpv[4];
#pragma unroll
        for (int r = 0; r < 4; r++) cpv[r] = __shfl(corr, fg * 4 + r, 64);
#pragma unroll
        for (int jj = 0; jj < 4; jj++)
#pragma unroll
          for (int r = 0; r < 4; r++) oA[jj][r] *= cpv[r];
#pragma unroll
        for (int r = 0; r < 4; r++) oLA[r] *= cpv[r];
      }
      s16x4 pb[4];
#pragma unroll
      for (int f = 0; f < 4; f++)
#pragma unroll
        for (int r = 0; r < 4; r++)
          pb[f][r] = f2b(fexp2(scA[f][r] - mA));
#pragma unroll
      for (int f = 0; f < 4; f++)
        *(s16x4*)(&PA[fr * 72 + f * 16 + fg * 4]) = pb[f];
    }
    // ---- PV (+ ones-column for l) ----
    {
      s16x8 paB0 = *(const s16x8*)(&PB[fr * 72 + fg * 8]);
      s16x8 paB1 = *(const s16x8*)(&PB[fr * 72 + 32 + fg * 8]);
#pragma unroll
      for (int jj = 0; jj < 4; jj++){
        oB[jj] = mf(paB0, v0[jj], oB[jj]);
        oB[jj] = mf(paB1, v1[jj], oB[jj]);
      }
      oLB = mf(paB0, ones, oLB);
      oLB = mf(paB1, ones, oLB);
    }
    if (Aact){
      s16x8 paA0 = *(const s16x8*)(&PA[fr * 72 + fg * 8]);
      s16x8 paA1 = *(const s16x8*)(&PA[fr * 72 + 32 + fg * 8]);
#pragma unroll
      for (int jj = 0; jj < 4; jj++){
        oA[jj] = mf(paA0, v0[jj], oA[jj]);
        oA[jj] = mf(paA1, v1[jj], oA[jj]);
      }
      oLA = mf(paA0, ones, oLA);
      oLA = mf(paA1, ones, oLA);
    }
    // ---- commit pipelined scores ----
    if (hasN){
#pragma unroll
      for (int f = 0; f < 4; f++) scB[f] = sNB[f];
      if (AactN){
#pragma unroll
        for (int f = 0; f < 4; f++) scA[f] = sNA[f];
      }
    }
  };

  int kv0 = 0;
  while (true){
    body(Kc0, Kc1, Kn0, Kn1, kv0); kv0 += 64; if (kv0 > qwB) break;
    body(Kn0, Kn1, Kc0, Kc1, kv0); kv0 += 64; if (kv0 > qwB) break;
  }

  const int b = bh >> 3, h = bh & 7;
  const int bperm = lane & 48;                 // lane (fr=0, same fg): holds l
  float lpv[4];
#pragma unroll
  for (int r = 0; r < 4; r++) lpv[r] = __shfl(oLB[r], bperm, 64);
#pragma unroll
  for (int jj = 0; jj < 4; jj++)
#pragma unroll
    for (int r = 0; r < 4; r++){
      int qq = qwB + fg * 4 + r;
      O[(size_t)(b * 1024 + qq) * 512 + h * 64 + jj * 16 + fr] = f2b(oB[jj][r] / lpv[r]);
    }
#pragma unroll
  for (int r = 0; r < 4; r++) lpv[r] = __shfl(oLA[r], bperm, 64);
#pragma unroll
  for (int jj = 0; jj < 4; jj++)
#pragma unroll
    for (int r = 0; r < 4; r++){
      int qq = qwA + fg * 4 + r;
      O[(size_t)(b * 1024 + qq) * 512 + h * 64 + jj * 16 + fr] = f2b(oA[jj][r] / lpv[r]);
    }
}

// ---------------- final GEMM: f32 out ----------------
__global__ __launch_bounds__(256) void k_gemm_out(const short* __restrict__ X,
                                                  const short* __restrict__ Wt,
                                                  float* __restrict__ C){
  __shared__ __align__(16) short Al[128 * 32];
  __shared__ __align__(16) short Bl[128 * 32];
  const int t = threadIdx.x;
  const int w = t >> 6, lane = t & 63, fr = lane & 15, fg = lane >> 4;
  const int bm = blockIdx.x * 128, bn = blockIdx.y * 128;
  const int wm = (w >> 1) * 64, wn = (w & 1) * 64;
  const int r8 = t >> 2, c8 = (t & 3) * 8;
  f32x4 acc[4][4] = {};
  for (int k0 = 0; k0 < 512; k0 += 32){
    __syncthreads();
#pragma unroll
    for (int j = 0; j < 2; j++){
      const short* ga = X  + (size_t)(bm + j * 64 + r8) * 512 + (k0 + c8);
      const short* gb = Wt + (size_t)(bn + j * 64 + r8) * 512 + (k0 + c8);
      gload_lds16(ga, &Al[j * 2048 + w * 512]);
      gload_lds16(gb, &Bl[j * 2048 + w * 512]);
    }
    __syncthreads();
    s16x8 af[4], bv[4];
#pragma unroll
    for (int f = 0; f < 4; f++){
      af[f] = *(const s16x8*)(&Al[(wm + f * 16 + fr) * 32 + fg * 8]);
      bv[f] = *(const s16x8*)(&Bl[(wn + f * 16 + fr) * 32 + fg * 8]);
    }
#pragma unroll
    for (int i = 0; i < 4; i++)
#pragma unroll
      for (int jj = 0; jj < 4; jj++)
        acc[i][jj] = __builtin_amdgcn_mfma_f32_16x16x32_bf16(as_bf(af[i]), as_bf(bv[jj]),
                                                             acc[i][jj], 0, 0, 0);
  }
  const int row0 = bm + wm + fg * 4;
  const int col0 = bn + wn + fr;
#pragma unroll
  for (int i = 0; i < 4; i++)
#pragma unroll
    for (int jj = 0; jj < 4; jj++)
#pragma unroll
      for (int r = 0; r < 4; r++)
        C[(size_t)(row0 + i * 16 + r) * 512 + col0 + jj * 16] = acc[i][jj][r];
}

extern "C" void kernel_launch(void* const* d_in, const int* in_sizes, int n_in,
                              void* d_out, int out_size, void* d_ws, size_t ws_size,
                              hipStream_t stream){
  const float* query  = (const float*)d_in[0];
  const float* value  = (const float*)d_in[1];
  const float* key_in = (const float*)d_in[2];
  const float* Wq     = (const float*)d_in[3];
  const float* Wk     = (const float*)d_in[4];
  const float* Wv     = (const float*)d_in[5];
  const float* Wo     = (const float*)d_in[6];

  char* ws = (char*)d_ws;
  const size_t MB = 1ull << 20;
  short* Xq   = (short*)(ws);                    // 8 MB  (later reused as O)
  short* Xk   = (short*)(ws + 8 * MB);           // 8 MB
  short* Xv   = (short*)(ws + 16 * MB);          // 8 MB
  short* Wcat = (short*)(ws + 24 * MB);          // 2 MB: Wq,Wk,Wv,Wo transposed
  float* tab  = (float*)(ws + 26 * MB);          // 256 KB
  short* Qa   = (short*)(ws + 26 * MB + 256 * 1024);   // 8 MB
  short* Ka   = (short*)((char*)Qa + 8 * MB);          // 8 MB
  short* Va   = (short*)((char*)Ka + 8 * MB);          // 8 MB  (ends at 50.25 MB)
  short* Oa   = Xq;
  short* Wot  = Wcat + 786432;                   // Wo^T block

  k_conv3<<<dim3(4096, 1, 3), 256, 0, stream>>>(query, key_in, value, Xq);
  k_wt4<<<dim3(16, 16, 4), dim3(32, 8), 0, stream>>>(Wq, Wk, Wv, Wo, Wcat);
  k_table<<<128, 256, 0, stream>>>(tab);

  k_qkv<<<dim3(64, 12), 256, 0, stream>>>(Xq, Xk, Xv, Wcat, tab, Qa, Ka, Va);

  k_attn<<<2048, 64, 0, stream>>>(Qa, Ka, Va, Oa);

  k_gemm_out<<<dim3(64, 4), 256, 0, stream>>>(Oa, Wot, (float*)d_out);
}